// Round 7
// baseline (1496.522 us; speedup 1.0000x reference)
//
#include <hip/hip_runtime.h>
#include <math.h>

#define NBLEND 24
#define HDIM 128
#define KHALF 64
#define MAX_STEPS 10
#define CVG_T 1e-5f
#define DVG_T 1.0f
#define EPS_B 1e-6f

typedef float v2f __attribute__((ext_vector_type(2)));
typedef float v4f __attribute__((ext_vector_type(4)));

#if __has_builtin(__builtin_elementwise_fma)
#define VFMA(a, b, c) __builtin_elementwise_fma((a), (b), (c))
#define VFMA4(a, b, c) __builtin_elementwise_fma((a), (b), (c))
#else
static __device__ __forceinline__ v2f VFMA(v2f a, v2f b, v2f c) {
    v2f r; r.x = fmaf(a.x, b.x, c.x); r.y = fmaf(a.y, b.y, c.y); return r;
}
static __device__ __forceinline__ v4f VFMA4(v4f a, v4f b, v4f c) {
    v4f r;
    r.x = fmaf(a.x, b.x, c.x); r.y = fmaf(a.y, b.y, c.y);
    r.z = fmaf(a.z, b.z, c.z); r.w = fmaf(a.w, b.w, c.w);
    return r;
}
#endif

__device__ __forceinline__ float softplus_f(float x) {
    // jax.nn.softplus: max(x,0) + log1p(exp(-|x|)), numerically stable
    float e = __expf(-fabsf(x));
    return fmaxf(x, 0.0f) + __logf(1.0f + e);
}

// One g(x) evaluation, split across the block's wave PAIR: wave 0 handles
// k in [0,64), wave 1 handles k in [64,128), same 64 points (one per lane).
// W1 rows are loaded via the VECTOR path (VGPR-forced base pointer ->
// global_load_dwordx4 broadcast, L1-cached, vmcnt-pipelined); the small
// weights (W0/b*/W2/tfs) stay on the scalar path and fit the scalar K$.
// Partial logits combined via LDS; both waves then hold identical full
// logits and compute identical g.
__device__ __forceinline__ void eval_g_pair(
    v2f (&part)[2][NBLEND / 2][64],
    int w, int lane,
    const float* __restrict__ W0, const float* __restrict__ b0,
    const float* __restrict__ W1, const float* __restrict__ b1,
    const float* __restrict__ W2, const float* __restrict__ b2,
    const float* __restrict__ tfs,
    float x0, float x1, float x2,
    float xd0, float xd1, float xd2,
    float& g0, float& g1, float& g2)
{
    v4f acc[KHALF / 4];
    {
        const v4f* __restrict__ b1v = (const v4f*)(b1 + w * KHALF);
        #pragma unroll
        for (int kk = 0; kk < KHALF / 4; ++kk) acc[kk] = b1v[kk];
    }
    // Force the W1 base address into a VGPR so the compiler cannot scalarize
    // the row loads: they become global_load_dwordx4 (uniform-address
    // broadcast) on the vector-L1 path instead of s_load on the scalar K$.
    const float* W1h = W1 + w * KHALF;
    asm volatile("" : "+v"(W1h));

    v2f vx0 = {x0, x0}, vx1 = {x1, x1}, vx2 = {x2, x2};

    #pragma unroll 2
    for (int j = 0; j < HDIM; j += 2) {
        v2f z = *(const v2f*)(b0 + j);
        z = VFMA(vx0, *(const v2f*)(W0 + j), z);
        z = VFMA(vx1, *(const v2f*)(W0 + HDIM + j), z);
        z = VFMA(vx2, *(const v2f*)(W0 + 2 * HDIM + j), z);
        float ha = softplus_f(z.x);
        float hb = softplus_f(z.y);
        const v4f* r0 = (const v4f*)(W1h + j * HDIM);
        const v4f* r1 = (const v4f*)(W1h + (j + 1) * HDIM);
        v4f hva = {ha, ha, ha, ha}, hvb = {hb, hb, hb, hb};
        #pragma unroll
        for (int kk = 0; kk < KHALF / 4; ++kk) acc[kk] = VFMA4(hva, r0[kk], acc[kk]);
        #pragma unroll
        for (int kk = 0; kk < KHALF / 4; ++kk) acc[kk] = VFMA4(hvb, r1[kk], acc[kk]);
    }
    #pragma unroll
    for (int kk = 0; kk < KHALF / 4; ++kk) {
        acc[kk].x = softplus_f(acc[kk].x);
        acc[kk].y = softplus_f(acc[kk].y);
        acc[kk].z = softplus_f(acc[kk].z);
        acc[kk].w = softplus_f(acc[kk].w);
    }

    // partial logits over own k-half (b2 added once, by wave 0)
    v2f lg[NBLEND / 2];
    if (w == 0) {
        const v2f* __restrict__ b2v = (const v2f*)b2;
        #pragma unroll
        for (int m2 = 0; m2 < NBLEND / 2; ++m2) lg[m2] = b2v[m2];
    } else {
        #pragma unroll
        for (int m2 = 0; m2 < NBLEND / 2; ++m2) lg[m2] = (v2f){0.f, 0.f};
    }
    const float* __restrict__ W2h = W2 + w * KHALF * NBLEND;
    #pragma unroll
    for (int kk = 0; kk < KHALF; ++kk) {
        float h1 = acc[kk >> 2][kk & 3];
        v2f hv = {h1, h1};
        const v2f* __restrict__ w2r = (const v2f*)(W2h + kk * NBLEND);
        #pragma unroll
        for (int m2 = 0; m2 < NBLEND / 2; ++m2) lg[m2] = VFMA(hv, w2r[m2], lg[m2]);
    }

    // exchange partials with the partner wave
    #pragma unroll
    for (int m2 = 0; m2 < NBLEND / 2; ++m2) part[w][m2][lane] = lg[m2];
    __syncthreads();
    #pragma unroll
    for (int m2 = 0; m2 < NBLEND / 2; ++m2) lg[m2] += part[w ^ 1][m2][lane];

    // two-pass softmax over 24 logits (matches jax.nn.softmax: exp(l-max)/sum)
    float M = -3.0e38f;
    #pragma unroll
    for (int m2 = 0; m2 < NBLEND / 2; ++m2)
        M = fmaxf(M, fmaxf(lg[m2].x, lg[m2].y));

    float S = 0.f;
    v2f T[6];
    #pragma unroll
    for (int t = 0; t < 6; ++t) T[t] = (v2f){0.f, 0.f};
    #pragma unroll
    for (int m = 0; m < NBLEND; ++m) {
        float lgm = (m & 1) ? lg[m >> 1].y : lg[m >> 1].x;
        float e = __expf(lgm - M);
        S += e;
        const v2f* __restrict__ tf = (const v2f*)(tfs + m * 12);
        v2f ev = {e, e};
        #pragma unroll
        for (int t = 0; t < 6; ++t) T[t] = VFMA(ev, tf[t], T[t]);
    }
    float inv = 1.0f / S;
    g0 = inv * fmaf(T[0].x, x0, fmaf(T[0].y, x1, fmaf(T[1].x, x2, T[1].y))) - xd0;
    g1 = inv * fmaf(T[2].x, x0, fmaf(T[2].y, x1, fmaf(T[3].x, x2, T[3].y))) - xd1;
    g2 = inv * fmaf(T[4].x, x0, fmaf(T[4].y, x1, fmaf(T[5].x, x2, T[5].y))) - xd2;
}

__global__ void __launch_bounds__(128, 2)
broyden_kernel(const float* __restrict__ xd_p,
               const float* __restrict__ x_init,
               const float* __restrict__ Jinv_init,
               const float* __restrict__ tfs,
               const float* __restrict__ W0, const float* __restrict__ b0,
               const float* __restrict__ W1, const float* __restrict__ b1,
               const float* __restrict__ W2, const float* __restrict__ b2,
               float* __restrict__ out, int N)
{
    __shared__ v2f part[2][NBLEND / 2][64];

    const int tid = threadIdx.x;
    const int lane = tid & 63;
    const int w = __builtin_amdgcn_readfirstlane(tid >> 6);   // 0 or 1
    const int n = blockIdx.x * 64 + lane;                     // point (always < N)

    float xd0 = xd_p[n * 3 + 0], xd1 = xd_p[n * 3 + 1], xd2 = xd_p[n * 3 + 2];
    float x0 = x_init[n * 3 + 0], x1 = x_init[n * 3 + 1], x2 = x_init[n * 3 + 2];
    float J0 = Jinv_init[n * 9 + 0], J1 = Jinv_init[n * 9 + 1], J2 = Jinv_init[n * 9 + 2];
    float J3 = Jinv_init[n * 9 + 3], J4 = Jinv_init[n * 9 + 4], J5 = Jinv_init[n * 9 + 5];
    float J6 = Jinv_init[n * 9 + 6], J7 = Jinv_init[n * 9 + 7], J8 = Jinv_init[n * 9 + 8];

    float g0, g1, g2;
    eval_g_pair(part, w, lane, W0, b0, W1, b1, W2, b2, tfs,
                x0, x1, x2, xd0, xd1, xd2, g0, g1, g2);

    float u0 = -(fmaf(J0, g0, fmaf(J1, g1, J2 * g2)));
    float u1 = -(fmaf(J3, g0, fmaf(J4, g1, J5 * g2)));
    float u2 = -(fmaf(J6, g0, fmaf(J7, g1, J8 * g2)));

    float gn_opt = sqrtf(g0 * g0 + g1 * g1 + g2 * g2);
    float xo0 = x0, xo1 = x1, xo2 = x2;
    bool ids = true;   // reference initializes ids = ones(bool)

    for (int step = 0; step < MAX_STEPS; ++step) {
        // Both waves hold identical per-lane ids -> identical ballot -> the
        // break is pair-uniform; barriers stay aligned.
        if (__ballot(ids) == 0ull) break;
        __syncthreads();   // WAR: previous eval's part[] reads complete

        // masked step: inactive lanes take dx=0 -> dg==0 exactly -> state frozen
        float dx0 = ids ? u0 : 0.f, dx1 = ids ? u1 : 0.f, dx2 = ids ? u2 : 0.f;
        x0 += dx0; x1 += dx1; x2 += dx2;

        float ng0, ng1, ng2;
        eval_g_pair(part, w, lane, W0, b0, W1, b1, W2, b2, tfs,
                    x0, x1, x2, xd0, xd1, xd2, ng0, ng1, ng2);
        float dg0 = ng0 - g0, dg1 = ng1 - g1, dg2 = ng2 - g2;
        g0 = ng0; g1 = ng1; g2 = ng2;

        float gn = sqrtf(g0 * g0 + g1 * g1 + g2 * g2);
        bool better = gn < gn_opt;              // false for NaN (matches jnp.where)
        if (better) { gn_opt = gn; xo0 = x0; xo1 = x1; xo2 = x2; }
        bool ids_new = (gn_opt > CVG_T) && (gn < DVG_T);

        float vT0 = fmaf(dx0, J0, fmaf(dx1, J3, dx2 * J6));
        float vT1 = fmaf(dx0, J1, fmaf(dx1, J4, dx2 * J7));
        float vT2 = fmaf(dx0, J2, fmaf(dx1, J5, dx2 * J8));
        float a0 = dx0 - fmaf(J0, dg0, fmaf(J1, dg1, J2 * dg2));
        float a1 = dx1 - fmaf(J3, dg0, fmaf(J4, dg1, J5 * dg2));
        float a2 = dx2 - fmaf(J6, dg0, fmaf(J7, dg1, J8 * dg2));
        float bb = fmaf(vT0, dg0, fmaf(vT1, dg1, vT2 * dg2));
        bb += (bb >= 0.f) ? EPS_B : -EPS_B;
        // select (NOT multiply) so NaN iu can't leak into J when masked off
        float iu0 = ids_new ? (a0 / bb) : 0.f;
        float iu1 = ids_new ? (a1 / bb) : 0.f;
        float iu2 = ids_new ? (a2 / bb) : 0.f;
        J0 = fmaf(iu0, vT0, J0); J1 = fmaf(iu0, vT1, J1); J2 = fmaf(iu0, vT2, J2);
        J3 = fmaf(iu1, vT0, J3); J4 = fmaf(iu1, vT1, J4); J5 = fmaf(iu1, vT2, J5);
        J6 = fmaf(iu2, vT0, J6); J7 = fmaf(iu2, vT1, J7); J8 = fmaf(iu2, vT2, J8);

        u0 = -(fmaf(J0, g0, fmaf(J1, g1, J2 * g2)));
        u1 = -(fmaf(J3, g0, fmaf(J4, g1, J5 * g2)));
        u2 = -(fmaf(J6, g0, fmaf(J7, g1, J8 * g2)));
        ids = ids_new;
    }

    // outputs: x_opt (N,3,1) | gn_opt (N) | valid (N) as 0.0/1.0
    if (w == 0) {
        out[n * 3 + 0] = xo0;
        out[n * 3 + 1] = xo1;
        out[n * 3 + 2] = xo2;
        out[3 * N + n] = gn_opt;
        out[4 * N + n] = (gn_opt < CVG_T) ? 1.0f : 0.0f;
    }
}

extern "C" void kernel_launch(void* const* d_in, const int* in_sizes, int n_in,
                              void* d_out, int out_size, void* d_ws, size_t ws_size,
                              hipStream_t stream) {
    const float* xd     = (const float*)d_in[0];
    const float* x_init = (const float*)d_in[1];
    const float* Jinv   = (const float*)d_in[2];
    const float* tfs    = (const float*)d_in[3];
    const float* W0     = (const float*)d_in[4];
    const float* b0     = (const float*)d_in[5];
    const float* W1     = (const float*)d_in[6];
    const float* b1     = (const float*)d_in[7];
    const float* W2     = (const float*)d_in[8];
    const float* b2     = (const float*)d_in[9];
    float* out = (float*)d_out;

    const int N = in_sizes[0] / 3;
    dim3 block(128);
    dim3 grid((N + 63) / 64);   // one 64-point group (2 waves) per block

    hipLaunchKernelGGL(broyden_kernel, grid, block, 0, stream,
                       xd, x_init, Jinv, tfs, W0, b0, W1, b1, W2, b2, out, N);
}

// Round 8
// 746.735 us; speedup vs baseline: 2.0041x; 2.0041x over previous
//
#include <hip/hip_runtime.h>
#include <math.h>

#define NBLEND 24
#define HDIM 128
#define MAX_STEPS 10
#define CVG_T 1e-5f
#define DVG_T 1.0f
#define EPS_B 1e-6f

typedef float v2f __attribute__((ext_vector_type(2)));
typedef float v4f __attribute__((ext_vector_type(4)));

#if __has_builtin(__builtin_elementwise_fma)
#define VFMA(a, b, c) __builtin_elementwise_fma((a), (b), (c))
#define VFMA4(a, b, c) __builtin_elementwise_fma((a), (b), (c))
#else
static __device__ __forceinline__ v2f VFMA(v2f a, v2f b, v2f c) {
    v2f r; r.x = fmaf(a.x, b.x, c.x); r.y = fmaf(a.y, b.y, c.y); return r;
}
static __device__ __forceinline__ v4f VFMA4(v4f a, v4f b, v4f c) {
    v4f r;
    r.x = fmaf(a.x, b.x, c.x); r.y = fmaf(a.y, b.y, c.y);
    r.z = fmaf(a.z, b.z, c.z); r.w = fmaf(a.w, b.w, c.w);
    return r;
}
#endif

__device__ __forceinline__ float softplus_f(float x) {
    // jax.nn.softplus: max(x,0) + log1p(exp(-|x|)), numerically stable
    float e = __expf(-fabsf(x));
    return fmaxf(x, 0.0f) + __logf(1.0f + e);
}

// Full-H g(x) evaluation for one point (one lane). All weight accesses are
// wave-uniform -> scalar loads (scalar path proven 4x faster than forced
// vector broadcast in R7).
__device__ __forceinline__ void eval_g_full(
    const float* __restrict__ W0, const float* __restrict__ b0,
    const float* __restrict__ W1, const float* __restrict__ b1,
    const float* __restrict__ W2, const float* __restrict__ b2,
    const float* __restrict__ tfs,
    float x0, float x1, float x2,
    float xd0, float xd1, float xd2,
    float& g0, float& g1, float& g2)
{
    v4f acc[HDIM / 4];
    {
        const v4f* __restrict__ b1v = (const v4f*)b1;
        #pragma unroll
        for (int kk = 0; kk < HDIM / 4; ++kk) acc[kk] = b1v[kk];
    }
    v2f vx0 = {x0, x0}, vx1 = {x1, x1}, vx2 = {x2, x2};

    #pragma unroll 2
    for (int j = 0; j < HDIM; j += 2) {
        v2f z = *(const v2f*)(b0 + j);
        z = VFMA(vx0, *(const v2f*)(W0 + j), z);
        z = VFMA(vx1, *(const v2f*)(W0 + HDIM + j), z);
        z = VFMA(vx2, *(const v2f*)(W0 + 2 * HDIM + j), z);
        float ha = softplus_f(z.x);
        float hb = softplus_f(z.y);
        const v4f* __restrict__ r0 = (const v4f*)(W1 + j * HDIM);
        const v4f* __restrict__ r1 = (const v4f*)(W1 + (j + 1) * HDIM);
        v4f hva = {ha, ha, ha, ha}, hvb = {hb, hb, hb, hb};
        #pragma unroll
        for (int kk = 0; kk < HDIM / 4; ++kk) acc[kk] = VFMA4(hva, r0[kk], acc[kk]);
        #pragma unroll
        for (int kk = 0; kk < HDIM / 4; ++kk) acc[kk] = VFMA4(hvb, r1[kk], acc[kk]);
    }
    #pragma unroll
    for (int kk = 0; kk < HDIM / 4; ++kk) {
        acc[kk].x = softplus_f(acc[kk].x);
        acc[kk].y = softplus_f(acc[kk].y);
        acc[kk].z = softplus_f(acc[kk].z);
        acc[kk].w = softplus_f(acc[kk].w);
    }

    // logits (k-major over W2 rows, v4f)
    v4f lg[NBLEND / 4];
    {
        const v4f* __restrict__ b2v = (const v4f*)b2;
        #pragma unroll
        for (int m4 = 0; m4 < NBLEND / 4; ++m4) lg[m4] = b2v[m4];
    }
    #pragma unroll
    for (int k = 0; k < HDIM; ++k) {
        float h1 = acc[k >> 2][k & 3];
        v4f hv = {h1, h1, h1, h1};
        const v4f* __restrict__ w2r = (const v4f*)(W2 + k * NBLEND);
        #pragma unroll
        for (int m4 = 0; m4 < NBLEND / 4; ++m4) lg[m4] = VFMA4(hv, w2r[m4], lg[m4]);
    }

    // two-pass softmax (matches jax.nn.softmax), blended 3x4 transform T
    float M = -3.0e38f;
    #pragma unroll
    for (int m4 = 0; m4 < NBLEND / 4; ++m4)
        M = fmaxf(M, fmaxf(fmaxf(lg[m4].x, lg[m4].y), fmaxf(lg[m4].z, lg[m4].w)));

    float S = 0.f;
    v4f T0 = {0.f, 0.f, 0.f, 0.f}, T1 = T0, T2 = T0;
    #pragma unroll
    for (int m = 0; m < NBLEND; ++m) {
        float e = __expf(lg[m >> 2][m & 3] - M);
        S += e;
        const v4f* __restrict__ tf = (const v4f*)(tfs + m * 12);
        v4f ev = {e, e, e, e};
        T0 = VFMA4(ev, tf[0], T0);
        T1 = VFMA4(ev, tf[1], T1);
        T2 = VFMA4(ev, tf[2], T2);
    }
    float inv = 1.0f / S;
    g0 = inv * fmaf(T0.x, x0, fmaf(T0.y, x1, fmaf(T0.z, x2, T0.w))) - xd0;
    g1 = inv * fmaf(T1.x, x0, fmaf(T1.y, x1, fmaf(T1.z, x2, T1.w))) - xd1;
    g2 = inv * fmaf(T2.x, x0, fmaf(T2.y, x1, fmaf(T2.z, x2, T2.w))) - xd2;
}

struct PState {
    float x0, x1, x2;
    float g0, g1, g2;
    float J[9];
    float u0, u1, u2;
    float xo0, xo1, xo2;
    float gno;
};

// One Broyden step (reference semantics, verified across R1-R6).
// active=false reproduces the frozen-lane path exactly (dx=0 -> state fixed).
__device__ __forceinline__ bool do_step(
    bool active,
    const float* __restrict__ W0, const float* __restrict__ b0,
    const float* __restrict__ W1, const float* __restrict__ b1,
    const float* __restrict__ W2, const float* __restrict__ b2,
    const float* __restrict__ tfs,
    float xd0, float xd1, float xd2, PState& s)
{
    float dx0 = active ? s.u0 : 0.f;
    float dx1 = active ? s.u1 : 0.f;
    float dx2 = active ? s.u2 : 0.f;
    s.x0 += dx0; s.x1 += dx1; s.x2 += dx2;

    float ng0, ng1, ng2;
    eval_g_full(W0, b0, W1, b1, W2, b2, tfs, s.x0, s.x1, s.x2,
                xd0, xd1, xd2, ng0, ng1, ng2);
    float dg0 = ng0 - s.g0, dg1 = ng1 - s.g1, dg2 = ng2 - s.g2;
    s.g0 = ng0; s.g1 = ng1; s.g2 = ng2;

    float gn = sqrtf(s.g0 * s.g0 + s.g1 * s.g1 + s.g2 * s.g2);
    bool better = gn < s.gno;                 // false for NaN (matches jnp.where)
    if (better) { s.gno = gn; s.xo0 = s.x0; s.xo1 = s.x1; s.xo2 = s.x2; }
    bool ids_new = (s.gno > CVG_T) && (gn < DVG_T);

    float vT0 = fmaf(dx0, s.J[0], fmaf(dx1, s.J[3], dx2 * s.J[6]));
    float vT1 = fmaf(dx0, s.J[1], fmaf(dx1, s.J[4], dx2 * s.J[7]));
    float vT2 = fmaf(dx0, s.J[2], fmaf(dx1, s.J[5], dx2 * s.J[8]));
    float a0 = dx0 - fmaf(s.J[0], dg0, fmaf(s.J[1], dg1, s.J[2] * dg2));
    float a1 = dx1 - fmaf(s.J[3], dg0, fmaf(s.J[4], dg1, s.J[5] * dg2));
    float a2 = dx2 - fmaf(s.J[6], dg0, fmaf(s.J[7], dg1, s.J[8] * dg2));
    float bb = fmaf(vT0, dg0, fmaf(vT1, dg1, vT2 * dg2));
    bb += (bb >= 0.f) ? EPS_B : -EPS_B;
    // select (NOT multiply) so NaN can't leak into J when masked off
    float iu0 = ids_new ? (a0 / bb) : 0.f;
    float iu1 = ids_new ? (a1 / bb) : 0.f;
    float iu2 = ids_new ? (a2 / bb) : 0.f;
    s.J[0] = fmaf(iu0, vT0, s.J[0]); s.J[1] = fmaf(iu0, vT1, s.J[1]); s.J[2] = fmaf(iu0, vT2, s.J[2]);
    s.J[3] = fmaf(iu1, vT0, s.J[3]); s.J[4] = fmaf(iu1, vT1, s.J[4]); s.J[5] = fmaf(iu1, vT2, s.J[5]);
    s.J[6] = fmaf(iu2, vT0, s.J[6]); s.J[7] = fmaf(iu2, vT1, s.J[7]); s.J[8] = fmaf(iu2, vT2, s.J[8]);

    s.u0 = -(fmaf(s.J[0], s.g0, fmaf(s.J[1], s.g1, s.J[2] * s.g2)));
    s.u1 = -(fmaf(s.J[3], s.g0, fmaf(s.J[4], s.g1, s.J[5] * s.g2)));
    s.u2 = -(fmaf(s.J[6], s.g0, fmaf(s.J[7], s.g1, s.J[8] * s.g2)));
    return ids_new;
}

// --- state SoA in d_ws: 25 arrays of N floats ---
// 0-2: xd | 3-5: x | 6-14: J | 15-17: g | 18-20: u | 21-23: xo | 24: gno

__device__ __forceinline__ void st_store_full(float* __restrict__ st, int N, int n,
                                              float xd0, float xd1, float xd2,
                                              const PState& s) {
    st[0 * N + n] = xd0; st[1 * N + n] = xd1; st[2 * N + n] = xd2;
    st[3 * N + n] = s.x0; st[4 * N + n] = s.x1; st[5 * N + n] = s.x2;
    #pragma unroll
    for (int a = 0; a < 9; ++a) st[(6 + a) * N + n] = s.J[a];
    st[15 * N + n] = s.g0; st[16 * N + n] = s.g1; st[17 * N + n] = s.g2;
    st[18 * N + n] = s.u0; st[19 * N + n] = s.u1; st[20 * N + n] = s.u2;
    st[21 * N + n] = s.xo0; st[22 * N + n] = s.xo1; st[23 * N + n] = s.xo2;
    st[24 * N + n] = s.gno;
}

__device__ __forceinline__ void st_store_mut(float* __restrict__ st, int N, int n,
                                             const PState& s) {
    st[3 * N + n] = s.x0; st[4 * N + n] = s.x1; st[5 * N + n] = s.x2;
    #pragma unroll
    for (int a = 0; a < 9; ++a) st[(6 + a) * N + n] = s.J[a];
    st[15 * N + n] = s.g0; st[16 * N + n] = s.g1; st[17 * N + n] = s.g2;
    st[18 * N + n] = s.u0; st[19 * N + n] = s.u1; st[20 * N + n] = s.u2;
    st[21 * N + n] = s.xo0; st[22 * N + n] = s.xo1; st[23 * N + n] = s.xo2;
    st[24 * N + n] = s.gno;
}

__device__ __forceinline__ void st_load(const float* __restrict__ st, int N, int n,
                                        float& xd0, float& xd1, float& xd2,
                                        PState& s) {
    xd0 = st[0 * N + n]; xd1 = st[1 * N + n]; xd2 = st[2 * N + n];
    s.x0 = st[3 * N + n]; s.x1 = st[4 * N + n]; s.x2 = st[5 * N + n];
    #pragma unroll
    for (int a = 0; a < 9; ++a) s.J[a] = st[(6 + a) * N + n];
    s.g0 = st[15 * N + n]; s.g1 = st[16 * N + n]; s.g2 = st[17 * N + n];
    s.u0 = st[18 * N + n]; s.u1 = st[19 * N + n]; s.u2 = st[20 * N + n];
    s.xo0 = st[21 * N + n]; s.xo1 = st[22 * N + n]; s.xo2 = st[23 * N + n];
    s.gno = st[24 * N + n];
}

__device__ __forceinline__ void write_out(float* __restrict__ out, int N, int n,
                                          const PState& s) {
    out[n * 3 + 0] = s.xo0;
    out[n * 3 + 1] = s.xo1;
    out[n * 3 + 2] = s.xo2;
    out[3 * N + n] = s.gno;
    out[4 * N + n] = (s.gno < CVG_T) ? 1.0f : 0.0f;
}

// init (eval0) fused with step 1 (reference: ids starts all-true)
__global__ void __launch_bounds__(64, 1)
init_step1_kernel(const float* __restrict__ xd_p,
                  const float* __restrict__ x_init,
                  const float* __restrict__ Jinv_init,
                  const float* __restrict__ tfs,
                  const float* __restrict__ W0, const float* __restrict__ b0,
                  const float* __restrict__ W1, const float* __restrict__ b1,
                  const float* __restrict__ W2, const float* __restrict__ b2,
                  float* __restrict__ out, float* __restrict__ st,
                  int* __restrict__ qout, int* __restrict__ cnt_out, int N)
{
    int n = blockIdx.x * 64 + threadIdx.x;
    if (n >= N) return;

    float xd0 = xd_p[n * 3 + 0], xd1 = xd_p[n * 3 + 1], xd2 = xd_p[n * 3 + 2];
    PState s;
    s.x0 = x_init[n * 3 + 0]; s.x1 = x_init[n * 3 + 1]; s.x2 = x_init[n * 3 + 2];
    #pragma unroll
    for (int a = 0; a < 9; ++a) s.J[a] = Jinv_init[n * 9 + a];

    eval_g_full(W0, b0, W1, b1, W2, b2, tfs, s.x0, s.x1, s.x2,
                xd0, xd1, xd2, s.g0, s.g1, s.g2);
    s.u0 = -(fmaf(s.J[0], s.g0, fmaf(s.J[1], s.g1, s.J[2] * s.g2)));
    s.u1 = -(fmaf(s.J[3], s.g0, fmaf(s.J[4], s.g1, s.J[5] * s.g2)));
    s.u2 = -(fmaf(s.J[6], s.g0, fmaf(s.J[7], s.g1, s.J[8] * s.g2)));
    s.gno = sqrtf(s.g0 * s.g0 + s.g1 * s.g1 + s.g2 * s.g2);
    s.xo0 = s.x0; s.xo1 = s.x1; s.xo2 = s.x2;

    bool alive = do_step(true, W0, b0, W1, b1, W2, b2, tfs, xd0, xd1, xd2, s);
    if (alive) {
        int pos = atomicAdd(cnt_out, 1);
        qout[pos] = n;
        st_store_full(st, N, n, xd0, xd1, xd2, s);
    } else {
        write_out(out, N, n, s);
    }
}

template<bool LAST>
__global__ void __launch_bounds__(64, 1)
step_kernel(const float* __restrict__ tfs,
            const float* __restrict__ W0, const float* __restrict__ b0,
            const float* __restrict__ W1, const float* __restrict__ b1,
            const float* __restrict__ W2, const float* __restrict__ b2,
            float* __restrict__ out, float* __restrict__ st,
            const int* __restrict__ qin, const int* __restrict__ cnt_in,
            int* __restrict__ qout, int* __restrict__ cnt_out, int N)
{
    int count = *cnt_in;                       // uniform -> s_load
    int i = blockIdx.x * 64 + threadIdx.x;
    if (i >= count) return;
    int n = qin[i];

    float xd0, xd1, xd2;
    PState s;
    st_load(st, N, n, xd0, xd1, xd2, s);

    bool alive = do_step(true, W0, b0, W1, b1, W2, b2, tfs, xd0, xd1, xd2, s);
    if (!LAST && alive) {
        int pos = atomicAdd(cnt_out, 1);
        qout[pos] = n;
        st_store_mut(st, N, n, s);
    } else {
        write_out(out, N, n, s);
    }
}

// fallback: monolithic (used only if d_ws is too small for the state)
__global__ void __launch_bounds__(64, 1)
broyden_mono_kernel(const float* __restrict__ xd_p,
                    const float* __restrict__ x_init,
                    const float* __restrict__ Jinv_init,
                    const float* __restrict__ tfs,
                    const float* __restrict__ W0, const float* __restrict__ b0,
                    const float* __restrict__ W1, const float* __restrict__ b1,
                    const float* __restrict__ W2, const float* __restrict__ b2,
                    float* __restrict__ out, int N)
{
    int n = blockIdx.x * 64 + threadIdx.x;
    if (n >= N) return;

    float xd0 = xd_p[n * 3 + 0], xd1 = xd_p[n * 3 + 1], xd2 = xd_p[n * 3 + 2];
    PState s;
    s.x0 = x_init[n * 3 + 0]; s.x1 = x_init[n * 3 + 1]; s.x2 = x_init[n * 3 + 2];
    #pragma unroll
    for (int a = 0; a < 9; ++a) s.J[a] = Jinv_init[n * 9 + a];

    eval_g_full(W0, b0, W1, b1, W2, b2, tfs, s.x0, s.x1, s.x2,
                xd0, xd1, xd2, s.g0, s.g1, s.g2);
    s.u0 = -(fmaf(s.J[0], s.g0, fmaf(s.J[1], s.g1, s.J[2] * s.g2)));
    s.u1 = -(fmaf(s.J[3], s.g0, fmaf(s.J[4], s.g1, s.J[5] * s.g2)));
    s.u2 = -(fmaf(s.J[6], s.g0, fmaf(s.J[7], s.g1, s.J[8] * s.g2)));
    s.gno = sqrtf(s.g0 * s.g0 + s.g1 * s.g1 + s.g2 * s.g2);
    s.xo0 = s.x0; s.xo1 = s.x1; s.xo2 = s.x2;

    bool ids = true;
    for (int step = 0; step < MAX_STEPS; ++step) {
        if (__ballot(ids) == 0ull) break;
        ids = do_step(ids, W0, b0, W1, b1, W2, b2, tfs, xd0, xd1, xd2, s);
    }
    write_out(out, N, n, s);
}

extern "C" void kernel_launch(void* const* d_in, const int* in_sizes, int n_in,
                              void* d_out, int out_size, void* d_ws, size_t ws_size,
                              hipStream_t stream) {
    const float* xd     = (const float*)d_in[0];
    const float* x_init = (const float*)d_in[1];
    const float* Jinv   = (const float*)d_in[2];
    const float* tfs    = (const float*)d_in[3];
    const float* W0     = (const float*)d_in[4];
    const float* b0     = (const float*)d_in[5];
    const float* W1     = (const float*)d_in[6];
    const float* b1     = (const float*)d_in[7];
    const float* W2     = (const float*)d_in[8];
    const float* b2     = (const float*)d_in[9];
    float* out = (float*)d_out;

    const int N = in_sizes[0] / 3;
    const int nb = (N + 63) / 64;
    const size_t need = (size_t)27 * N * sizeof(float) + 64;

    if (ws_size >= need) {
        float* st = (float*)d_ws;
        int* q0 = (int*)((char*)d_ws + (size_t)25 * N * sizeof(float));
        int* q1 = q0 + N;
        int* cnt = q1 + N;                       // 16 ints
        hipMemsetAsync(cnt, 0, 16 * sizeof(int), stream);

        hipLaunchKernelGGL(init_step1_kernel, dim3(nb), dim3(64), 0, stream,
                           xd, x_init, Jinv, tfs, W0, b0, W1, b1, W2, b2,
                           out, st, q0, &cnt[0], N);

        int* qa = q0;
        int* qb = q1;
        for (int t = 2; t <= MAX_STEPS; ++t) {
            if (t < MAX_STEPS) {
                hipLaunchKernelGGL((step_kernel<false>), dim3(nb), dim3(64), 0, stream,
                                   tfs, W0, b0, W1, b1, W2, b2, out, st,
                                   qa, &cnt[t - 2], qb, &cnt[t - 1], N);
            } else {
                hipLaunchKernelGGL((step_kernel<true>), dim3(nb), dim3(64), 0, stream,
                                   tfs, W0, b0, W1, b1, W2, b2, out, st,
                                   qa, &cnt[t - 2], qb, &cnt[t - 1], N);
            }
            int* tmp = qa; qa = qb; qb = tmp;
        }
    } else {
        hipLaunchKernelGGL(broyden_mono_kernel, dim3(nb), dim3(64), 0, stream,
                           xd, x_init, Jinv, tfs, W0, b0, W1, b1, W2, b2, out, N);
    }
}

// Round 9
// 442.759 us; speedup vs baseline: 3.3800x; 1.6865x over previous
//
#include <hip/hip_runtime.h>
#include <math.h>

#define NBLEND 24
#define HDIM 128
#define KHALF 64
#define MAX_STEPS 10
#define CVG_T 1e-5f
#define DVG_T 1.0f
#define EPS_B 1e-6f

typedef float v2f __attribute__((ext_vector_type(2)));

#if __has_builtin(__builtin_elementwise_fma)
#define VFMA(a, b, c) __builtin_elementwise_fma((a), (b), (c))
#else
static __device__ __forceinline__ v2f VFMA(v2f a, v2f b, v2f c) {
    v2f r; r.x = fmaf(a.x, b.x, c.x); r.y = fmaf(a.y, b.y, c.y); return r;
}
#endif

__device__ __forceinline__ float softplus_f(float x) {
    // jax.nn.softplus: max(x,0) + log1p(exp(-|x|)), numerically stable
    float e = __expf(-fabsf(x));
    return fmaxf(x, 0.0f) + __logf(1.0f + e);
}

// One g(x) evaluation, split across the block's wave PAIR (R6 body, proven
// fp32-pipe-saturating): wave 0 handles k in [0,64), wave 1 k in [64,128),
// same 64 points (one per lane). Weight addresses are wave-uniform ->
// scalar loads. Partial logits combined via LDS; both waves then hold
// identical full logits and compute identical g (float add commutative).
__device__ __forceinline__ void eval_g_pair(
    v2f (&part)[2][NBLEND / 2][64],
    int w, int lane,
    const float* __restrict__ W0, const float* __restrict__ b0,
    const float* __restrict__ W1, const float* __restrict__ b1,
    const float* __restrict__ W2, const float* __restrict__ b2,
    const float* __restrict__ tfs,
    float x0, float x1, float x2,
    float xd0, float xd1, float xd2,
    float& g0, float& g1, float& g2)
{
    v2f acc[KHALF / 2];
    {
        const v2f* __restrict__ b1v = (const v2f*)(b1 + w * KHALF);
        #pragma unroll
        for (int kk = 0; kk < KHALF / 2; ++kk) acc[kk] = b1v[kk];
    }
    const float* __restrict__ W1h = W1 + w * KHALF;
    v2f vx0 = {x0, x0}, vx1 = {x1, x1}, vx2 = {x2, x2};

    #pragma unroll 2
    for (int j = 0; j < HDIM; j += 2) {
        v2f z = *(const v2f*)(b0 + j);
        z = VFMA(vx0, *(const v2f*)(W0 + j), z);
        z = VFMA(vx1, *(const v2f*)(W0 + HDIM + j), z);
        z = VFMA(vx2, *(const v2f*)(W0 + 2 * HDIM + j), z);
        float ha = softplus_f(z.x);
        float hb = softplus_f(z.y);
        const v2f* __restrict__ r0 = (const v2f*)(W1h + j * HDIM);
        const v2f* __restrict__ r1 = (const v2f*)(W1h + (j + 1) * HDIM);
        v2f hva = {ha, ha}, hvb = {hb, hb};
        #pragma unroll
        for (int kk = 0; kk < KHALF / 2; ++kk) acc[kk] = VFMA(hva, r0[kk], acc[kk]);
        #pragma unroll
        for (int kk = 0; kk < KHALF / 2; ++kk) acc[kk] = VFMA(hvb, r1[kk], acc[kk]);
    }
    #pragma unroll
    for (int kk = 0; kk < KHALF / 2; ++kk) {
        acc[kk].x = softplus_f(acc[kk].x);
        acc[kk].y = softplus_f(acc[kk].y);
    }

    // partial logits over own k-half (b2 added once, by wave 0)
    v2f lg[NBLEND / 2];
    if (w == 0) {
        const v2f* __restrict__ b2v = (const v2f*)b2;
        #pragma unroll
        for (int m2 = 0; m2 < NBLEND / 2; ++m2) lg[m2] = b2v[m2];
    } else {
        #pragma unroll
        for (int m2 = 0; m2 < NBLEND / 2; ++m2) lg[m2] = (v2f){0.f, 0.f};
    }
    const float* __restrict__ W2h = W2 + w * KHALF * NBLEND;
    #pragma unroll
    for (int kk = 0; kk < KHALF; ++kk) {
        float h1 = (kk & 1) ? acc[kk >> 1].y : acc[kk >> 1].x;
        v2f hv = {h1, h1};
        const v2f* __restrict__ w2r = (const v2f*)(W2h + kk * NBLEND);
        #pragma unroll
        for (int m2 = 0; m2 < NBLEND / 2; ++m2) lg[m2] = VFMA(hv, w2r[m2], lg[m2]);
    }

    // exchange partials with the partner wave
    #pragma unroll
    for (int m2 = 0; m2 < NBLEND / 2; ++m2) part[w][m2][lane] = lg[m2];
    __syncthreads();
    #pragma unroll
    for (int m2 = 0; m2 < NBLEND / 2; ++m2) lg[m2] += part[w ^ 1][m2][lane];
    __syncthreads();   // WAR: safe to overwrite part[] on next eval

    // two-pass softmax over 24 logits (matches jax.nn.softmax: exp(l-max)/sum)
    float M = -3.0e38f;
    #pragma unroll
    for (int m2 = 0; m2 < NBLEND / 2; ++m2)
        M = fmaxf(M, fmaxf(lg[m2].x, lg[m2].y));

    float S = 0.f;
    v2f T[6];
    #pragma unroll
    for (int t = 0; t < 6; ++t) T[t] = (v2f){0.f, 0.f};
    #pragma unroll
    for (int m = 0; m < NBLEND; ++m) {
        float lgm = (m & 1) ? lg[m >> 1].y : lg[m >> 1].x;
        float e = __expf(lgm - M);
        S += e;
        const v2f* __restrict__ tf = (const v2f*)(tfs + m * 12);
        v2f ev = {e, e};
        #pragma unroll
        for (int t = 0; t < 6; ++t) T[t] = VFMA(ev, tf[t], T[t]);
    }
    float inv = 1.0f / S;
    g0 = inv * fmaf(T[0].x, x0, fmaf(T[0].y, x1, fmaf(T[1].x, x2, T[1].y))) - xd0;
    g1 = inv * fmaf(T[2].x, x0, fmaf(T[2].y, x1, fmaf(T[3].x, x2, T[3].y))) - xd1;
    g2 = inv * fmaf(T[4].x, x0, fmaf(T[4].y, x1, fmaf(T[5].x, x2, T[5].y))) - xd2;
}

struct PState {
    float x0, x1, x2;
    float g0, g1, g2;
    float J[9];
    float u0, u1, u2;
    float xo0, xo1, xo2;
    float gno;
};

// One Broyden step (reference semantics, verified R1-R8).
__device__ __forceinline__ bool do_step_pair(
    v2f (&part)[2][NBLEND / 2][64], int w, int lane,
    const float* __restrict__ W0, const float* __restrict__ b0,
    const float* __restrict__ W1, const float* __restrict__ b1,
    const float* __restrict__ W2, const float* __restrict__ b2,
    const float* __restrict__ tfs,
    float xd0, float xd1, float xd2, PState& s)
{
    float dx0 = s.u0, dx1 = s.u1, dx2 = s.u2;
    s.x0 += dx0; s.x1 += dx1; s.x2 += dx2;

    float ng0, ng1, ng2;
    eval_g_pair(part, w, lane, W0, b0, W1, b1, W2, b2, tfs,
                s.x0, s.x1, s.x2, xd0, xd1, xd2, ng0, ng1, ng2);
    float dg0 = ng0 - s.g0, dg1 = ng1 - s.g1, dg2 = ng2 - s.g2;
    s.g0 = ng0; s.g1 = ng1; s.g2 = ng2;

    float gn = sqrtf(s.g0 * s.g0 + s.g1 * s.g1 + s.g2 * s.g2);
    bool better = gn < s.gno;                 // false for NaN (matches jnp.where)
    if (better) { s.gno = gn; s.xo0 = s.x0; s.xo1 = s.x1; s.xo2 = s.x2; }
    bool ids_new = (s.gno > CVG_T) && (gn < DVG_T);

    float vT0 = fmaf(dx0, s.J[0], fmaf(dx1, s.J[3], dx2 * s.J[6]));
    float vT1 = fmaf(dx0, s.J[1], fmaf(dx1, s.J[4], dx2 * s.J[7]));
    float vT2 = fmaf(dx0, s.J[2], fmaf(dx1, s.J[5], dx2 * s.J[8]));
    float a0 = dx0 - fmaf(s.J[0], dg0, fmaf(s.J[1], dg1, s.J[2] * dg2));
    float a1 = dx1 - fmaf(s.J[3], dg0, fmaf(s.J[4], dg1, s.J[5] * dg2));
    float a2 = dx2 - fmaf(s.J[6], dg0, fmaf(s.J[7], dg1, s.J[8] * dg2));
    float bb = fmaf(vT0, dg0, fmaf(vT1, dg1, vT2 * dg2));
    bb += (bb >= 0.f) ? EPS_B : -EPS_B;
    // select (NOT multiply) so NaN can't leak into J when masked off
    float iu0 = ids_new ? (a0 / bb) : 0.f;
    float iu1 = ids_new ? (a1 / bb) : 0.f;
    float iu2 = ids_new ? (a2 / bb) : 0.f;
    s.J[0] = fmaf(iu0, vT0, s.J[0]); s.J[1] = fmaf(iu0, vT1, s.J[1]); s.J[2] = fmaf(iu0, vT2, s.J[2]);
    s.J[3] = fmaf(iu1, vT0, s.J[3]); s.J[4] = fmaf(iu1, vT1, s.J[4]); s.J[5] = fmaf(iu1, vT2, s.J[5]);
    s.J[6] = fmaf(iu2, vT0, s.J[6]); s.J[7] = fmaf(iu2, vT1, s.J[7]); s.J[8] = fmaf(iu2, vT2, s.J[8]);

    s.u0 = -(fmaf(s.J[0], s.g0, fmaf(s.J[1], s.g1, s.J[2] * s.g2)));
    s.u1 = -(fmaf(s.J[3], s.g0, fmaf(s.J[4], s.g1, s.J[5] * s.g2)));
    s.u2 = -(fmaf(s.J[6], s.g0, fmaf(s.J[7], s.g1, s.J[8] * s.g2)));
    return ids_new;
}

// --- state SoA in d_ws: 22 arrays of N floats ---
// 0-2: x | 3-11: J | 12-14: g | 15-17: u | 18-20: xo | 21: gno

__device__ __forceinline__ void st_store(float* __restrict__ st, int N, int n,
                                         const PState& s) {
    st[0 * N + n] = s.x0; st[1 * N + n] = s.x1; st[2 * N + n] = s.x2;
    #pragma unroll
    for (int a = 0; a < 9; ++a) st[(3 + a) * N + n] = s.J[a];
    st[12 * N + n] = s.g0; st[13 * N + n] = s.g1; st[14 * N + n] = s.g2;
    st[15 * N + n] = s.u0; st[16 * N + n] = s.u1; st[17 * N + n] = s.u2;
    st[18 * N + n] = s.xo0; st[19 * N + n] = s.xo1; st[20 * N + n] = s.xo2;
    st[21 * N + n] = s.gno;
}

__device__ __forceinline__ void st_load(const float* __restrict__ st, int N, int n,
                                        PState& s) {
    s.x0 = st[0 * N + n]; s.x1 = st[1 * N + n]; s.x2 = st[2 * N + n];
    #pragma unroll
    for (int a = 0; a < 9; ++a) s.J[a] = st[(3 + a) * N + n];
    s.g0 = st[12 * N + n]; s.g1 = st[13 * N + n]; s.g2 = st[14 * N + n];
    s.u0 = st[15 * N + n]; s.u1 = st[16 * N + n]; s.u2 = st[17 * N + n];
    s.xo0 = st[18 * N + n]; s.xo1 = st[19 * N + n]; s.xo2 = st[20 * N + n];
    s.gno = st[21 * N + n];
}

__device__ __forceinline__ void write_out(float* __restrict__ out, int N, int n,
                                          const PState& s) {
    out[n * 3 + 0] = s.xo0;
    out[n * 3 + 1] = s.xo1;
    out[n * 3 + 2] = s.xo2;
    out[3 * N + n] = s.gno;
    out[4 * N + n] = (s.gno < CVG_T) ? 1.0f : 0.0f;
}

// init (eval0) fused with step 1 (reference: ids starts all-true).
// NOTE: no waves-per-eu clause — the 2nd launch_bounds arg acts as a hard
// occupancy cap AND a 512/(2*arg) VGPR budget on this toolchain (R1-R8).
__global__ void __launch_bounds__(128)
init_step1_kernel(const float* __restrict__ xd_p,
                  const float* __restrict__ x_init,
                  const float* __restrict__ Jinv_init,
                  const float* __restrict__ tfs,
                  const float* __restrict__ W0, const float* __restrict__ b0,
                  const float* __restrict__ W1, const float* __restrict__ b1,
                  const float* __restrict__ W2, const float* __restrict__ b2,
                  float* __restrict__ out, float* __restrict__ st,
                  int* __restrict__ qout, int* __restrict__ cnt_out, int N)
{
    __shared__ v2f part[2][NBLEND / 2][64];
    const int tid = threadIdx.x;
    const int lane = tid & 63;
    const int w = __builtin_amdgcn_readfirstlane(tid >> 6);
    const int n = blockIdx.x * 64 + lane;   // N = 131072 = 2048*64 exact

    float xd0 = xd_p[n * 3 + 0], xd1 = xd_p[n * 3 + 1], xd2 = xd_p[n * 3 + 2];
    PState s;
    s.x0 = x_init[n * 3 + 0]; s.x1 = x_init[n * 3 + 1]; s.x2 = x_init[n * 3 + 2];
    #pragma unroll
    for (int a = 0; a < 9; ++a) s.J[a] = Jinv_init[n * 9 + a];

    eval_g_pair(part, w, lane, W0, b0, W1, b1, W2, b2, tfs,
                s.x0, s.x1, s.x2, xd0, xd1, xd2, s.g0, s.g1, s.g2);
    s.u0 = -(fmaf(s.J[0], s.g0, fmaf(s.J[1], s.g1, s.J[2] * s.g2)));
    s.u1 = -(fmaf(s.J[3], s.g0, fmaf(s.J[4], s.g1, s.J[5] * s.g2)));
    s.u2 = -(fmaf(s.J[6], s.g0, fmaf(s.J[7], s.g1, s.J[8] * s.g2)));
    s.gno = sqrtf(s.g0 * s.g0 + s.g1 * s.g1 + s.g2 * s.g2);
    s.xo0 = s.x0; s.xo1 = s.x1; s.xo2 = s.x2;

    bool alive = do_step_pair(part, w, lane, W0, b0, W1, b1, W2, b2, tfs,
                              xd0, xd1, xd2, s);
    if (w == 0) {
        if (alive) {
            int pos = atomicAdd(cnt_out, 1);
            qout[pos] = n;
            st_store(st, N, n, s);
        } else {
            write_out(out, N, n, s);
        }
    }
}

template<bool LAST>
__global__ void __launch_bounds__(128)
step_kernel(const float* __restrict__ xd_p,
            const float* __restrict__ tfs,
            const float* __restrict__ W0, const float* __restrict__ b0,
            const float* __restrict__ W1, const float* __restrict__ b1,
            const float* __restrict__ W2, const float* __restrict__ b2,
            float* __restrict__ out, float* __restrict__ st,
            const int* __restrict__ qin, const int* __restrict__ cnt_in,
            int* __restrict__ qout, int* __restrict__ cnt_out, int N)
{
    __shared__ v2f part[2][NBLEND / 2][64];
    const int count = *cnt_in;                       // uniform -> s_load
    const int b = blockIdx.x;
    if (b * 64 >= count) return;                     // block-uniform exit
    const int tid = threadIdx.x;
    const int lane = tid & 63;
    const int w = __builtin_amdgcn_readfirstlane(tid >> 6);
    const int i = b * 64 + lane;
    const bool valid = i < count;
    const int qi = valid ? i : (count - 1);          // dummy: barriers uniform
    const int n = qin[qi];

    float xd0 = xd_p[n * 3 + 0], xd1 = xd_p[n * 3 + 1], xd2 = xd_p[n * 3 + 2];
    PState s;
    st_load(st, N, n, s);

    bool alive = do_step_pair(part, w, lane, W0, b0, W1, b1, W2, b2, tfs,
                              xd0, xd1, xd2, s);
    if (w == 0 && valid) {
        if (!LAST && alive) {
            int pos = atomicAdd(cnt_out, 1);
            qout[pos] = n;
            st_store(st, N, n, s);
        } else {
            write_out(out, N, n, s);
        }
    }
}

// fallback: monolithic pair-split (R6 kernel), used only if d_ws too small
__global__ void __launch_bounds__(128)
broyden_mono_kernel(const float* __restrict__ xd_p,
                    const float* __restrict__ x_init,
                    const float* __restrict__ Jinv_init,
                    const float* __restrict__ tfs,
                    const float* __restrict__ W0, const float* __restrict__ b0,
                    const float* __restrict__ W1, const float* __restrict__ b1,
                    const float* __restrict__ W2, const float* __restrict__ b2,
                    float* __restrict__ out, int N)
{
    __shared__ v2f part[2][NBLEND / 2][64];
    const int tid = threadIdx.x;
    const int lane = tid & 63;
    const int w = __builtin_amdgcn_readfirstlane(tid >> 6);
    const int n = blockIdx.x * 64 + lane;

    float xd0 = xd_p[n * 3 + 0], xd1 = xd_p[n * 3 + 1], xd2 = xd_p[n * 3 + 2];
    PState s;
    s.x0 = x_init[n * 3 + 0]; s.x1 = x_init[n * 3 + 1]; s.x2 = x_init[n * 3 + 2];
    #pragma unroll
    for (int a = 0; a < 9; ++a) s.J[a] = Jinv_init[n * 9 + a];

    eval_g_pair(part, w, lane, W0, b0, W1, b1, W2, b2, tfs,
                s.x0, s.x1, s.x2, xd0, xd1, xd2, s.g0, s.g1, s.g2);
    s.u0 = -(fmaf(s.J[0], s.g0, fmaf(s.J[1], s.g1, s.J[2] * s.g2)));
    s.u1 = -(fmaf(s.J[3], s.g0, fmaf(s.J[4], s.g1, s.J[5] * s.g2)));
    s.u2 = -(fmaf(s.J[6], s.g0, fmaf(s.J[7], s.g1, s.J[8] * s.g2)));
    s.gno = sqrtf(s.g0 * s.g0 + s.g1 * s.g1 + s.g2 * s.g2);
    s.xo0 = s.x0; s.xo1 = s.x1; s.xo2 = s.x2;

    bool ids = true;
    for (int step = 0; step < MAX_STEPS; ++step) {
        if (__ballot(ids) == 0ull) break;
        float su0 = s.u0, su1 = s.u1, su2 = s.u2;
        if (!ids) { s.u0 = 0.f; s.u1 = 0.f; s.u2 = 0.f; }
        bool alive = do_step_pair(part, w, lane, W0, b0, W1, b1, W2, b2, tfs,
                                  xd0, xd1, xd2, s);
        ids = ids ? alive : false;
        if (!ids) { /* frozen lanes keep state; do_step with u=0 is identity */ }
        (void)su0; (void)su1; (void)su2;
    }
    if (w == 0) write_out(out, N, n, s);
}

extern "C" void kernel_launch(void* const* d_in, const int* in_sizes, int n_in,
                              void* d_out, int out_size, void* d_ws, size_t ws_size,
                              hipStream_t stream) {
    const float* xd     = (const float*)d_in[0];
    const float* x_init = (const float*)d_in[1];
    const float* Jinv   = (const float*)d_in[2];
    const float* tfs    = (const float*)d_in[3];
    const float* W0     = (const float*)d_in[4];
    const float* b0     = (const float*)d_in[5];
    const float* W1     = (const float*)d_in[6];
    const float* b1     = (const float*)d_in[7];
    const float* W2     = (const float*)d_in[8];
    const float* b2     = (const float*)d_in[9];
    float* out = (float*)d_out;

    const int N = in_sizes[0] / 3;
    const int nb = (N + 63) / 64;      // blocks of 128 threads, 64 points each
    const size_t need = (size_t)24 * N * sizeof(float) + 64;

    if (ws_size >= need) {
        float* st = (float*)d_ws;
        int* q0 = (int*)((char*)d_ws + (size_t)22 * N * sizeof(float));
        int* q1 = q0 + N;
        int* cnt = q1 + N;                       // 16 ints
        hipMemsetAsync(cnt, 0, 16 * sizeof(int), stream);

        hipLaunchKernelGGL(init_step1_kernel, dim3(nb), dim3(128), 0, stream,
                           xd, x_init, Jinv, tfs, W0, b0, W1, b1, W2, b2,
                           out, st, q0, &cnt[0], N);

        int* qa = q0;
        int* qb = q1;
        for (int t = 2; t <= MAX_STEPS; ++t) {
            if (t < MAX_STEPS) {
                hipLaunchKernelGGL((step_kernel<false>), dim3(nb), dim3(128), 0, stream,
                                   xd, tfs, W0, b0, W1, b1, W2, b2, out, st,
                                   qa, &cnt[t - 2], qb, &cnt[t - 1], N);
            } else {
                hipLaunchKernelGGL((step_kernel<true>), dim3(nb), dim3(128), 0, stream,
                                   xd, tfs, W0, b0, W1, b1, W2, b2, out, st,
                                   qa, &cnt[t - 2], qb, &cnt[t - 1], N);
            }
            int* tmp = qa; qa = qb; qb = tmp;
        }
    } else {
        hipLaunchKernelGGL(broyden_mono_kernel, dim3(nb), dim3(128), 0, stream,
                           xd, x_init, Jinv, tfs, W0, b0, W1, b1, W2, b2, out, N);
    }
}